// Round 14
// baseline (65.097 us; speedup 1.0000x reference)
//
#include <hip/hip_runtime.h>

// Resample 48k -> 10k: up=5, down=24, 481-tap FIR.
// y[5k+d] = sum_{c=0..14,u=0..7} T[c*40+d*8+u] * x[24k-48+8c+u]
// T[c*40+d*8+u] = 5*h[24d+480-5*(8c+u)]  (c,d compile-time -> SGPR s_load)
//
// R14: producer/consumer wave specialization, FUSED-LOOP form.
// Same theory as R12 (dur ~= VALU+DS+HBM, zero overlap; fix = wave0 stages
// tile t+1 while wave1 computes tile t; raw s_barrier does NOT drain vmcnt
// so next-tile loads stay in flight). Structural change vs R12: no barrier
// lives inside divergent control flow — one s_barrier site, executed n+1
// times by every thread from the same program point -> deadlock impossible
// even if role code diverges. lgkmcnt(0) before each barrier makes the
// producer's ds_writes visible; vmcnt deliberately NOT drained.
//
// LDS: pad 4 per 16 (m = e + (e>>4)*4), 1.25x — 8-aligned chunks stay
// contiguous AND 16B-aligned -> 2x ds_read_b128 per chunk, ds_write_b128
// staging. 2 x 2040 floats = 16.3 kB -> ~9 blocks/CU. Grid 73x32.

#define NIN    1440000
#define NOUTR  300000
#define NROWS  32
#define KTOT   60000
#define NCHUNK 938               // ceil(KTOT/64): 64-k tiles per row
#define S      13                // tiles per block
#define NBX    73                // ceil(938/13); max cbase=936 -> n>=1 always
#define TILE   1632              // 24*63 + 120 floats
#define NV4    (TILE / 4)        // 408 float4s = 6*64 + 24
#define PADT   2040              // TILE + (TILE/16)*4  (pad-4-per-16, 1.25x)
#define TAPN   600

__global__ void prep_taps_kernel(const float* __restrict__ h, float* __restrict__ T) {
    int i = blockIdx.x * blockDim.x + threadIdx.x;
    if (i < TAPN) {
        int u = i & 7;
        int d = (i >> 3) % 5;
        int c = i / 40;
        int t = 24 * d + 480 - 5 * (c * 8 + u);
        T[i] = (t >= 0 && t <= 480) ? h[t] * 5.0f : 0.0f;
    }
}

template<int C>
__device__ __forceinline__ void chunk_mac(const float* __restrict__ L,
                                          const float* __restrict__ T,
                                          int lane, float2 acc[5]) {
    const int e0 = 24 * lane + 8 * C;        // 8-aligned chunk start
    const int m0 = e0 + ((e0 >> 4) << 2);    // contiguous 8, 16B-aligned
    const float4 va = *reinterpret_cast<const float4*>(L + m0);
    const float4 vb = *reinterpret_cast<const float4*>(L + m0 + 4);
    const float2 xv0 = make_float2(va.x, va.y);
    const float2 xv1 = make_float2(va.z, va.w);
    const float2 xv2 = make_float2(vb.x, vb.y);
    const float2 xv3 = make_float2(vb.z, vb.w);
    #pragma unroll
    for (int d = 0; d < 5; ++d) {
        // compile-time skip of all-zero tap groups (C,d constants)
        if (24 * d + 480 - 40 * C >= 0 && 24 * d + 445 - 40 * C <= 480) {
            const float2* __restrict__ tp =
                reinterpret_cast<const float2*>(T + C * 40 + d * 8);
            const float2 t0 = tp[0], t1 = tp[1], t2 = tp[2], t3 = tp[3];
            asm("v_pk_fma_f32 %0, %1, %2, %0" : "+v"(acc[d]) : "s"(t0), "v"(xv0));
            asm("v_pk_fma_f32 %0, %1, %2, %0" : "+v"(acc[d]) : "s"(t1), "v"(xv1));
            asm("v_pk_fma_f32 %0, %1, %2, %0" : "+v"(acc[d]) : "s"(t2), "v"(xv2));
            asm("v_pk_fma_f32 %0, %1, %2, %0" : "+v"(acc[d]) : "s"(t3), "v"(xv3));
        }
    }
}

__global__ __launch_bounds__(128, 5) void resample_kernel(
    const float* __restrict__ x, const float* __restrict__ T, float* __restrict__ y)
{
    __shared__ __align__(16) float lds[2 * PADT];
    const int tid   = threadIdx.x;
    const int lane  = tid & 63;
    const int wid   = tid >> 6;              // 0 = producer, 1 = consumer
    const int row   = blockIdx.y;
    const int cbase = blockIdx.x * S;
    const int n     = min(S, NCHUNK - cbase);   // >=1, uniform per block
    const float* __restrict__ xr = x + (size_t)row * NIN;

    float4 pf0, pf1, pf2, pf3, pf4, pf5, pf6;   // producer-only live regs

    auto load_tile = [&](int c) {
        const int g0 = 1536 * c - 48;            // 16B-aligned
        if (g0 >= 0 && g0 + TILE <= NIN) {       // interior fast path
            const float4* __restrict__ p = reinterpret_cast<const float4*>(xr + g0);
            pf0 = p[lane];       pf1 = p[lane + 64];  pf2 = p[lane + 128];
            pf3 = p[lane + 192]; pf4 = p[lane + 256]; pf5 = p[lane + 320];
            if (lane < NV4 - 384) pf6 = p[lane + 384];
        } else {                                  // first/last tiles only
            auto ld = [&](int i4) {
                const int g = g0 + 4 * i4; float4 v;
                v.x = ((unsigned)(g + 0) < NIN) ? xr[g + 0] : 0.f;
                v.y = ((unsigned)(g + 1) < NIN) ? xr[g + 1] : 0.f;
                v.z = ((unsigned)(g + 2) < NIN) ? xr[g + 2] : 0.f;
                v.w = ((unsigned)(g + 3) < NIN) ? xr[g + 3] : 0.f;
                return v;
            };
            pf0 = ld(lane);       pf1 = ld(lane + 64);  pf2 = ld(lane + 128);
            pf3 = ld(lane + 192); pf4 = ld(lane + 256); pf5 = ld(lane + 320);
            if (lane < NV4 - 384) pf6 = ld(lane + 384);
        }
    };

    auto write_tile = [&](int b) {               // ds_write_b128, swizzled
        float* __restrict__ L = lds + b * PADT;
        auto st = [&](const float4& v, int i4) {
            const int e = 4 * i4;
            const int m = e + ((e >> 4) << 2);   // 16B-aligned, contiguous
            *reinterpret_cast<float4*>(L + m) = v;
        };
        st(pf0, lane);       st(pf1, lane + 64);  st(pf2, lane + 128);
        st(pf3, lane + 192); st(pf4, lane + 256); st(pf5, lane + 320);
        if (lane < NV4 - 384) st(pf6, lane + 384);
    };

    // Prologue: producer fills buf0, issues loads for tile 1.
    if (wid == 0) {
        load_tile(cbase);
        write_tile(0);
        if (n > 1) load_tile(cbase + 1);         // stays in flight across barrier
    }
    asm volatile("s_waitcnt lgkmcnt(0)" ::: "memory");
    __builtin_amdgcn_s_barrier();                // single site, everyone: 1

    for (int t = 0; t < n; ++t) {
        if (wid == 0) {
            // Producer: land tile t+1 into the other buffer, prefetch t+2.
            if (t + 1 < n) {
                write_tile((t + 1) & 1);         // consumer reads buf t&1 now
                if (t + 2 < n) load_tile(cbase + t + 2);
            }
        } else {
            // Consumer: compute tile t from buf t&1.
            const int c = cbase + t;
            const float* __restrict__ L = lds + (t & 1) * PADT;

            float2 acc[5];
            #pragma unroll
            for (int d = 0; d < 5; ++d) acc[d] = make_float2(0.f, 0.f);

            chunk_mac< 0>(L, T, lane, acc);
            chunk_mac< 1>(L, T, lane, acc);
            chunk_mac< 2>(L, T, lane, acc);
            chunk_mac< 3>(L, T, lane, acc);
            chunk_mac< 4>(L, T, lane, acc);
            chunk_mac< 5>(L, T, lane, acc);
            chunk_mac< 6>(L, T, lane, acc);
            chunk_mac< 7>(L, T, lane, acc);
            chunk_mac< 8>(L, T, lane, acc);
            chunk_mac< 9>(L, T, lane, acc);
            chunk_mac<10>(L, T, lane, acc);
            chunk_mac<11>(L, T, lane, acc);
            chunk_mac<12>(L, T, lane, acc);
            chunk_mac<13>(L, T, lane, acc);
            chunk_mac<14>(L, T, lane, acc);

            const int k = 64 * c + lane;
            if (k < KTOT) {
                float* __restrict__ yr = y + (size_t)row * NOUTR + (size_t)5 * k;
                yr[0] = acc[0].x + acc[0].y;
                yr[1] = acc[1].x + acc[1].y;
                yr[2] = acc[2].x + acc[2].y;
                yr[3] = acc[3].x + acc[3].y;
                yr[4] = acc[4].x + acc[4].y;
            }
        }
        asm volatile("s_waitcnt lgkmcnt(0)" ::: "memory");
        __builtin_amdgcn_s_barrier();            // same single site: n more
    }
}

extern "C" void kernel_launch(void* const* d_in, const int* in_sizes, int n_in,
                              void* d_out, int out_size, void* d_ws, size_t ws_size,
                              hipStream_t stream) {
    const float* x = (const float*)d_in[0];
    const float* h = (const float*)d_in[1];   // 481 taps
    float* y = (float*)d_out;                 // 32 x 300000 f32
    float* T = (float*)d_ws;                  // 600 floats of scratch

    prep_taps_kernel<<<3, 256, 0, stream>>>(h, T);
    dim3 grid(NBX, NROWS);                    // 73 x 32 producer/consumer blocks
    resample_kernel<<<grid, 128, 0, stream>>>(x, T, y);
}

// Round 16
// 56.139 us; speedup vs baseline: 1.1596x; 1.1596x over previous
//
#include <hip/hip_runtime.h>

// Resample 48k -> 10k: up=5, down=24, 481-tap FIR.
// y[5k+d] = sum_{c=0..14,u=0..7} T[c*40+d*8+u] * x[24k-48+8c+u]
// T[c*40+d*8+u] = 5*h[24d+480-5*(8c+u)]  (c,d compile-time -> SGPR s_load)
//
// R15 (resubmit; infra failure) = R11 (best: 49.3us; 2-wave blocks,
// even/odd chunk split, 30 waves/CU) + S-tile persistence + REGISTER
// PREFETCH ACROSS RAW BARRIERS.
// R14 lesson: producer/consumer halves computing waves -> worse. Keep all
// waves computing; hide HBM instead: issue tile t+1's global loads BEFORE
// compute(t); raw s_barrier (no implicit vmcnt drain, unlike __syncthreads
// -- the R4 failure) means the vmcnt wait lands at the ds_write AFTER the
// post-compute barrier -> HBM hides under ~1500cy of compute.
// Two raw barriers/tile, lgkmcnt(0) only. All barrier sites block-uniform.
//
// LDS: xbuf pad-2-per-8 (conflict-free b64 window reads) 2040 floats
// + reduce 584 floats (stride-9 scalar slots, 9 coprime 32 -> conflict-free)
// = 10496 B -> 15 blocks/CU = 30 waves/CU.

#define NIN    1440000
#define NOUTR  300000
#define NROWS  32
#define KTOT   60000
#define NCHUNK 938               // ceil(KTOT/64): 64-k tiles per row
#define S      8                 // tiles per block
#define NBX    118               // ceil(938/8); grid 118x32=3776 ~ co-resident
#define TILE   1632              // 24*63 + 120 floats
#define NV4    (TILE / 4)        // 408 float4s = 3*128 + 24
#define PADT   2040              // TILE + (TILE/8)*2  (pad-2-per-8, 1.25x)
#define LDSN   (PADT + 584)      // + 64*9+5 reduce floats -> 10496 B
#define TAPN   600

__global__ void prep_taps_kernel(const float* __restrict__ h, float* __restrict__ T) {
    int i = blockIdx.x * blockDim.x + threadIdx.x;
    if (i < TAPN) {
        int u = i & 7;
        int d = (i >> 3) % 5;
        int c = i / 40;
        int t = 24 * d + 480 - 5 * (c * 8 + u);
        T[i] = (t >= 0 && t <= 480) ? h[t] * 5.0f : 0.0f;
    }
}

template<int C>
__device__ __forceinline__ void chunk_mac(const float* __restrict__ L,
                                          const float* __restrict__ T,
                                          int base, float2 acc[5]) {
    const int m0 = base + 10 * C;       // e0=24*lane+8C -> m=e0+(e0>>3)*2
    const float2 xv0 = *reinterpret_cast<const float2*>(L + m0);
    const float2 xv1 = *reinterpret_cast<const float2*>(L + m0 + 2);
    const float2 xv2 = *reinterpret_cast<const float2*>(L + m0 + 4);
    const float2 xv3 = *reinterpret_cast<const float2*>(L + m0 + 6);
    #pragma unroll
    for (int d = 0; d < 5; ++d) {
        // compile-time skip of all-zero tap groups (C,d constants)
        if (24 * d + 480 - 40 * C >= 0 && 24 * d + 445 - 40 * C <= 480) {
            const float2* __restrict__ tp =
                reinterpret_cast<const float2*>(T + C * 40 + d * 8);
            const float2 t0 = tp[0], t1 = tp[1], t2 = tp[2], t3 = tp[3];
            asm("v_pk_fma_f32 %0, %1, %2, %0" : "+v"(acc[d]) : "s"(t0), "v"(xv0));
            asm("v_pk_fma_f32 %0, %1, %2, %0" : "+v"(acc[d]) : "s"(t1), "v"(xv1));
            asm("v_pk_fma_f32 %0, %1, %2, %0" : "+v"(acc[d]) : "s"(t2), "v"(xv2));
            asm("v_pk_fma_f32 %0, %1, %2, %0" : "+v"(acc[d]) : "s"(t3), "v"(xv3));
        }
    }
}

__global__ __launch_bounds__(128, 8) void resample_kernel(
    const float* __restrict__ x, const float* __restrict__ T, float* __restrict__ y)
{
    __shared__ float lds[LDSN];
    const int tid   = threadIdx.x;
    const int lane  = tid & 63;
    const int wid   = tid >> 6;              // wave-uniform 0/1
    const int row   = blockIdx.y;
    const int cbase = blockIdx.x * S;
    const int n     = min(S, NCHUNK - cbase);   // >=1, block-uniform
    const float* __restrict__ xr = x + (size_t)row * NIN;

    float4 pf0, pf1, pf2, pf3;               // prefetch regs (128-thread split)

    auto load_tile = [&](int c) {            // issue 3-4 global float4 loads
        const int g0 = 1536 * c - 48;        // 16B-aligned
        if (g0 >= 0 && g0 + TILE <= NIN) {   // interior fast path
            const float4* __restrict__ p = reinterpret_cast<const float4*>(xr + g0);
            pf0 = p[tid];
            pf1 = p[tid + 128];
            pf2 = p[tid + 256];
            if (tid < NV4 - 384) pf3 = p[tid + 384];
        } else {                              // first/last tiles only
            auto ld = [&](int i4) {
                const int g = g0 + 4 * i4; float4 v;
                v.x = ((unsigned)(g + 0) < NIN) ? xr[g + 0] : 0.f;
                v.y = ((unsigned)(g + 1) < NIN) ? xr[g + 1] : 0.f;
                v.z = ((unsigned)(g + 2) < NIN) ? xr[g + 2] : 0.f;
                v.w = ((unsigned)(g + 3) < NIN) ? xr[g + 3] : 0.f;
                return v;
            };
            pf0 = ld(tid);
            pf1 = ld(tid + 128);
            pf2 = ld(tid + 256);
            if (tid < NV4 - 384) pf3 = ld(tid + 384);
        }
    };

    auto write_tile = [&]() {                // pad-2-per-8 swizzled stores
        auto st = [&](const float4& v, int i4) {
            const int e = i4 * 4;
            const int m = e + ((e >> 3) << 1);   // 8B-aligned float2 pairs
            *reinterpret_cast<float2*>(&lds[m])     = make_float2(v.x, v.y);
            *reinterpret_cast<float2*>(&lds[m + 2]) = make_float2(v.z, v.w);
        };
        st(pf0, tid);
        st(pf1, tid + 128);
        st(pf2, tid + 256);
        if (tid < NV4 - 384) st(pf3, tid + 384);
    };

    // Prologue: fill xbuf with tile 0.
    load_tile(cbase);
    write_tile();                            // vmcnt waited via reg dependence
    asm volatile("s_waitcnt lgkmcnt(0)" ::: "memory");
    __builtin_amdgcn_s_barrier();

    for (int t = 0; t < n; ++t) {
        if (t + 1 < n) load_tile(cbase + t + 1);   // ISSUE ONLY: flies over compute

        float2 acc[5];
        #pragma unroll
        for (int d = 0; d < 5; ++d) acc[d] = make_float2(0.f, 0.f);

        const int base = 30 * lane;
        if (wid == 0) {                      // even chunks: 33 active groups
            chunk_mac< 0>(lds, T, base, acc);
            chunk_mac< 2>(lds, T, base, acc);
            chunk_mac< 4>(lds, T, base, acc);
            chunk_mac< 6>(lds, T, base, acc);
            chunk_mac< 8>(lds, T, base, acc);
            chunk_mac<10>(lds, T, base, acc);
            chunk_mac<12>(lds, T, base, acc);
            chunk_mac<14>(lds, T, base, acc);
        } else {                             // odd chunks: 32 active groups
            chunk_mac< 1>(lds, T, base, acc);
            chunk_mac< 3>(lds, T, base, acc);
            chunk_mac< 5>(lds, T, base, acc);
            chunk_mac< 7>(lds, T, base, acc);
            chunk_mac< 9>(lds, T, base, acc);
            chunk_mac<11>(lds, T, base, acc);
            chunk_mac<13>(lds, T, base, acc);
        }

        if (wid == 1) {                      // stride-9 slots: conflict-free b32
            float* __restrict__ rp = &lds[PADT + 9 * lane];
            rp[0] = acc[0].x + acc[0].y;
            rp[1] = acc[1].x + acc[1].y;
            rp[2] = acc[2].x + acc[2].y;
            rp[3] = acc[3].x + acc[3].y;
            rp[4] = acc[4].x + acc[4].y;
        }
        asm volatile("s_waitcnt lgkmcnt(0)" ::: "memory");
        __builtin_amdgcn_s_barrier();        // B1: xbuf reads + partials done

        if (wid == 0) {
            const int k = 64 * (cbase + t) + lane;
            if (k < KTOT) {
                const float* __restrict__ rp = &lds[PADT + 9 * lane];
                float* __restrict__ yr = y + (size_t)row * NOUTR + (size_t)5 * k;
                yr[0] = acc[0].x + acc[0].y + rp[0];
                yr[1] = acc[1].x + acc[1].y + rp[1];
                yr[2] = acc[2].x + acc[2].y + rp[2];
                yr[3] = acc[3].x + acc[3].y + rp[3];
                yr[4] = acc[4].x + acc[4].y + rp[4];
            }
        }
        if (t + 1 < n) write_tile();         // vmcnt wait lands HERE (post-compute)
        asm volatile("s_waitcnt lgkmcnt(0)" ::: "memory");
        __builtin_amdgcn_s_barrier();        // B2: xbuf(t+1) visible to all
    }
}

extern "C" void kernel_launch(void* const* d_in, const int* in_sizes, int n_in,
                              void* d_out, int out_size, void* d_ws, size_t ws_size,
                              hipStream_t stream) {
    const float* x = (const float*)d_in[0];
    const float* h = (const float*)d_in[1];   // 481 taps
    float* y = (float*)d_out;                 // 32 x 300000 f32
    float* T = (float*)d_ws;                  // 600 floats of scratch

    prep_taps_kernel<<<3, 256, 0, stream>>>(h, T);
    dim3 grid(NBX, NROWS);                    // 118 x 32 two-wave blocks
    resample_kernel<<<grid, 128, 0, stream>>>(x, T, y);
}

// Round 17
// 54.161 us; speedup vs baseline: 1.2019x; 1.0365x over previous
//
#include <hip/hip_runtime.h>

// Resample 48k -> 10k: up=5, down=24, 481-tap FIR.
// Thread handles k-pair p: outputs y[10p..10p+9] (k=2p even, k=2p+1 odd).
// Union window: x[48p-48 .. 48p+96) = 144 floats = 18 chunks of 8 -> 40%
// fewer LDS bytes/instrs per output than 1-k-per-lane (windows overlap 96/120).
// Chunk J feeds k_even via tap group c=J (J<=14) and k_odd via c=J-3 (J>=3);
// all compile-time -> SGPR taps + v_pk_fma_f32 (R7 win) retained.
//
// R17 rationale: 5 overlap schemes failed (R4/R9/R14/R15); only serial-work
// cuts and wave count ever moved time. DS was the largest sum term (~19us of
// 49.3): KPT=2 + b128 cuts it to ~10us. 2-wave chunk split (wave0 even J,
// wave1 odd J — 15 group-sides each, balanced) + stride-11 scalar reduce.
//
// LDS: pad-4-per-16 swizzle (m = e + (e>>4)*4): every 8-aligned chunk stays
// contiguous + 16B-aligned -> 2x ds_read_b128 / chunk; b128 lane-stride 240B
// -> start banks cover all 32 per 8 lanes (conflict-free); staging is single
// ds_write_b128 per float4. 3960 + 712 floats = 18.7 kB -> 8 blocks/CU.

#define NIN    1440000
#define NOUTR  300000
#define NROWS  32
#define KTOT   60000
#define NPAIR  30000             // k-pairs total per row
#define PPB    64                // k-pairs per block (1 per lane)
#define NBX    469               // ceil(30000/64); last block: 48 valid pairs
#define TILE2  3168              // 48*63 + 144 floats
#define NV4    792               // TILE2/4 float4s = 6*128 + 24
#define PADT   3960              // TILE2 * 1.25 (pad-4-per-16)
#define REDS   11                // reduce slot stride (2-way banks = free)
#define LDSN   (PADT + 64*REDS + 8)   // 4672 floats = 18688 B
#define TAPN   600

__global__ void prep_taps_kernel(const float* __restrict__ h, float* __restrict__ T) {
    int i = blockIdx.x * blockDim.x + threadIdx.x;
    if (i < TAPN) {
        int u = i & 7;
        int d = (i >> 3) % 5;
        int c = i / 40;
        int t = 24 * d + 480 - 5 * (c * 8 + u);
        T[i] = (t >= 0 && t <= 480) ? h[t] * 5.0f : 0.0f;
    }
}

template<int C>
__device__ __forceinline__ void mac_group(const float* __restrict__ T,
                                          const float2 xv[4], float2 acc[5]) {
    #pragma unroll
    for (int d = 0; d < 5; ++d) {
        // compile-time skip of all-zero tap groups (C,d constants)
        if (24 * d + 480 - 40 * C >= 0 && 24 * d + 445 - 40 * C <= 480) {
            const float2* __restrict__ tp =
                reinterpret_cast<const float2*>(T + C * 40 + d * 8);
            const float2 t0 = tp[0], t1 = tp[1], t2 = tp[2], t3 = tp[3];
            asm("v_pk_fma_f32 %0, %1, %2, %0" : "+v"(acc[d]) : "s"(t0), "v"(xv[0]));
            asm("v_pk_fma_f32 %0, %1, %2, %0" : "+v"(acc[d]) : "s"(t1), "v"(xv[1]));
            asm("v_pk_fma_f32 %0, %1, %2, %0" : "+v"(acc[d]) : "s"(t2), "v"(xv[2]));
            asm("v_pk_fma_f32 %0, %1, %2, %0" : "+v"(acc[d]) : "s"(t3), "v"(xv[3]));
        }
    }
}

template<int J>
__device__ __forceinline__ void chunk_do(const float* __restrict__ L,
                                         const float* __restrict__ T,
                                         int lane, float2 accE[5], float2 accO[5]) {
    const int e0 = 48 * lane + 8 * J;        // 8-aligned chunk start (unswizzled)
    const int m0 = e0 + ((e0 >> 4) << 2);    // swizzled: contiguous 8, 16B-aligned
    const float4 va = *reinterpret_cast<const float4*>(L + m0);
    const float4 vb = *reinterpret_cast<const float4*>(L + m0 + 4);
    const float2 xv[4] = { make_float2(va.x, va.y), make_float2(va.z, va.w),
                           make_float2(vb.x, vb.y), make_float2(vb.z, vb.w) };
    if constexpr (J <= 14) mac_group<J>(T, xv, accE);      // k_even, c = J
    if constexpr (J >= 3)  mac_group<J - 3>(T, xv, accO);  // k_odd,  c = J-3
}

__global__ __launch_bounds__(128, 5) void resample_kernel(
    const float* __restrict__ x, const float* __restrict__ T, float* __restrict__ y)
{
    __shared__ __align__(16) float lds[LDSN];
    const int tid  = threadIdx.x;
    const int lane = tid & 63;
    const int wid  = tid >> 6;               // wave-uniform 0/1
    const int row  = blockIdx.y;
    const int bx   = blockIdx.x;
    const float* __restrict__ xr = x + (size_t)row * NIN;
    const int g0 = 3072 * bx - 48;           // tile start; 16B-aligned

    // Stage tile: float4 loads -> single swizzled ds_write_b128 each.
    if (g0 >= 0 && g0 + TILE2 <= NIN) {      // interior fast path
        #pragma unroll
        for (int j = 0; j < 7; ++j) {
            const int i4 = tid + 128 * j;
            if (j < 6 || i4 < NV4) {
                const int e = 4 * i4;
                const float4 v = *reinterpret_cast<const float4*>(xr + g0 + e);
                const int m = e + ((e >> 4) << 2);
                *reinterpret_cast<float4*>(&lds[m]) = v;
            }
        }
    } else {                                  // first/last blocks only
        #pragma unroll
        for (int j = 0; j < 7; ++j) {
            const int i4 = tid + 128 * j;
            if (j < 6 || i4 < NV4) {
                const int e = 4 * i4;
                const int g = g0 + e;
                float4 v;
                v.x = ((unsigned)(g + 0) < NIN) ? xr[g + 0] : 0.0f;
                v.y = ((unsigned)(g + 1) < NIN) ? xr[g + 1] : 0.0f;
                v.z = ((unsigned)(g + 2) < NIN) ? xr[g + 2] : 0.0f;
                v.w = ((unsigned)(g + 3) < NIN) ? xr[g + 3] : 0.0f;
                const int m = e + ((e >> 4) << 2);
                *reinterpret_cast<float4*>(&lds[m]) = v;
            }
        }
    }
    __syncthreads();

    float2 accE[5], accO[5];
    #pragma unroll
    for (int d = 0; d < 5; ++d) { accE[d] = make_float2(0.f, 0.f); accO[d] = make_float2(0.f, 0.f); }

    if (wid == 0) {                          // even chunks
        chunk_do< 0>(lds, T, lane, accE, accO);
        chunk_do< 2>(lds, T, lane, accE, accO);
        chunk_do< 4>(lds, T, lane, accE, accO);
        chunk_do< 6>(lds, T, lane, accE, accO);
        chunk_do< 8>(lds, T, lane, accE, accO);
        chunk_do<10>(lds, T, lane, accE, accO);
        chunk_do<12>(lds, T, lane, accE, accO);
        chunk_do<14>(lds, T, lane, accE, accO);
        chunk_do<16>(lds, T, lane, accE, accO);
    } else {                                 // odd chunks
        chunk_do< 1>(lds, T, lane, accE, accO);
        chunk_do< 3>(lds, T, lane, accE, accO);
        chunk_do< 5>(lds, T, lane, accE, accO);
        chunk_do< 7>(lds, T, lane, accE, accO);
        chunk_do< 9>(lds, T, lane, accE, accO);
        chunk_do<11>(lds, T, lane, accE, accO);
        chunk_do<13>(lds, T, lane, accE, accO);
        chunk_do<15>(lds, T, lane, accE, accO);
        chunk_do<17>(lds, T, lane, accE, accO);
    }

    float pe[5], po[5];
    #pragma unroll
    for (int d = 0; d < 5; ++d) {
        pe[d] = accE[d].x + accE[d].y;
        po[d] = accO[d].x + accO[d].y;
    }

    if (wid == 1) {                          // stride-11 scalar slots: 2-way = free
        float* __restrict__ rp = &lds[PADT + REDS * lane];
        rp[0] = pe[0]; rp[1] = pe[1]; rp[2] = pe[2]; rp[3] = pe[3]; rp[4] = pe[4];
        rp[5] = po[0]; rp[6] = po[1]; rp[7] = po[2]; rp[8] = po[3]; rp[9] = po[4];
    }
    __syncthreads();

    if (wid == 0) {
        const int p = PPB * bx + lane;       // k-pair index
        if (p < NPAIR) {
            const float* __restrict__ rp = &lds[PADT + REDS * lane];
            float* __restrict__ yr = y + (size_t)row * NOUTR + (size_t)10 * p;
            *reinterpret_cast<float2*>(yr + 0) = make_float2(pe[0] + rp[0], pe[1] + rp[1]);
            *reinterpret_cast<float2*>(yr + 2) = make_float2(pe[2] + rp[2], pe[3] + rp[3]);
            *reinterpret_cast<float2*>(yr + 4) = make_float2(pe[4] + rp[4], po[0] + rp[5]);
            *reinterpret_cast<float2*>(yr + 6) = make_float2(po[1] + rp[6], po[2] + rp[7]);
            *reinterpret_cast<float2*>(yr + 8) = make_float2(po[3] + rp[8], po[4] + rp[9]);
        }
    }
}

extern "C" void kernel_launch(void* const* d_in, const int* in_sizes, int n_in,
                              void* d_out, int out_size, void* d_ws, size_t ws_size,
                              hipStream_t stream) {
    const float* x = (const float*)d_in[0];
    const float* h = (const float*)d_in[1];   // 481 taps
    float* y = (float*)d_out;                 // 32 x 300000 f32
    float* T = (float*)d_ws;                  // 600 floats of scratch

    prep_taps_kernel<<<3, 256, 0, stream>>>(h, T);
    dim3 grid(NBX, NROWS);                    // 469 x 32 two-wave blocks
    resample_kernel<<<grid, 128, 0, stream>>>(x, T, y);
}

// Round 18
// 43.510 us; speedup vs baseline: 1.4961x; 1.2448x over previous
//
#include <hip/hip_runtime.h>

// Resample 48k -> 10k via MFMA: up=5, down=24, 481-tap FIR.
// y[5k+d] = sum_{c=0..119} Tap[c][d] * x[24k-48+c],  Tap[c][d]=5h[24d+480-5c]
// Cast as 16x16 tiles: Y(16k x 16cols, 5 used) = A(16x128) * B(128x16),
//   A[r][c] = bf16(x[24(k0+r)-48+c])  (K padded 120->128 with zero taps)
// mfma_f32_16x16x32_bf16 x4 K-chunks. A fragment = 8 contiguous bf16 =
// ONE ds_read_b128/lane/chunk (lane: row=l&15, k=8*(l>>4)+j). B constant
// in 16 VGPRs (prep-packed per-lane table). C/D: col=l&15, row=(l>>4)*4+reg
// [m89-verified]. DS instrs drop ~5x, VALU ~10x vs pk_fma formulation.
// bf16 rounding error ~6e-4 sigma, max ~3.5e-3 << 7.8e-3 tolerance.

#define NIN    1440000
#define NOUTR  300000
#define NROWS  32
#define KTOT   60000
#define NCHUNK 938               // 64-k tiles per row
#define S      8                 // tiles per block
#define NBX    118               // ceil(938/8)
#define TILE_E 1632              // 24*63+120 x-elems per tile
#define TILE_P 1648              // +16 zero pad (A reads c up to 127 -> le 1639)
#define NV4    408               // float4 loads per tile

typedef __attribute__((ext_vector_type(8))) short short8v;
typedef __attribute__((ext_vector_type(4))) float float4v;

__device__ __forceinline__ unsigned short f2b(float f) {
    unsigned u = __builtin_bit_cast(unsigned, f);
    u += 0x7fff + ((u >> 16) & 1);                 // round-to-nearest-even
    return (unsigned short)(u >> 16);
}

// Pack B fragments exactly as lanes consume them:
// Bpk[(m*64+l)*8+j] = bf16( Tap[c=32m+8*(l>>4)+j][d=l&15] ), 4KB in ws.
__global__ void prep_taps_kernel(const float* __restrict__ h,
                                 unsigned short* __restrict__ Bpk) {
    int i = blockIdx.x * blockDim.x + threadIdx.x;     // 0..2047
    if (i < 2048) {
        int j = i & 7, l = (i >> 3) & 63, m = i >> 9;
        int d = l & 15, q = l >> 4;
        int c = 32 * m + 8 * q + j;
        int t = 24 * d + 480 - 5 * c;
        float v = (d < 5 && t >= 0 && t <= 480) ? h[t] * 5.0f : 0.0f;
        Bpk[i] = f2b(v);
    }
}

__global__ __launch_bounds__(256, 6) void resample_kernel(
    const float* __restrict__ x, const unsigned short* __restrict__ Bpk,
    float* __restrict__ y)
{
    __shared__ short ldsb[TILE_P];                 // bf16 bits
    const int tid  = threadIdx.x;
    const int lane = tid & 63;
    const int wv   = tid >> 6;                     // 0..3: 16-k group per wave
    const int row  = blockIdx.y;
    const int cb   = blockIdx.x * S;
    const float* __restrict__ xr = x + (size_t)row * NIN;

    // B fragments: 4 global b128 loads (L2-hot 4KB table), constant all tiles.
    short8v B0 = *reinterpret_cast<const short8v*>(Bpk + (0 * 64 + lane) * 8);
    short8v B1 = *reinterpret_cast<const short8v*>(Bpk + (1 * 64 + lane) * 8);
    short8v B2 = *reinterpret_cast<const short8v*>(Bpk + (2 * 64 + lane) * 8);
    short8v B3 = *reinterpret_cast<const short8v*>(Bpk + (3 * 64 + lane) * 8);

    if (tid < TILE_P - TILE_E) ldsb[TILE_E + tid] = 0;   // zero pad: 0*NaN guard

    auto stc = [&](int i4, float4 v) {             // cvt 4xf32 -> 4xbf16, 8B write
        unsigned lo = (unsigned)f2b(v.x) | ((unsigned)f2b(v.y) << 16);
        unsigned hi = (unsigned)f2b(v.z) | ((unsigned)f2b(v.w) << 16);
        *reinterpret_cast<uint2*>(&ldsb[4 * i4]) = make_uint2(lo, hi);
    };

    for (int s = 0; s < S; ++s) {
        const int ct = cb + s;                     // block-uniform
        if (ct >= NCHUNK) break;                   // uniform break
        const long g0 = 1536L * ct - 48;

        __syncthreads();                           // prior tile's reads done
        if (g0 >= 0 && g0 + TILE_E <= NIN) {       // interior fast path
            const float4* __restrict__ p = reinterpret_cast<const float4*>(xr + g0);
            stc(tid, p[tid]);
            if (tid < NV4 - 256) stc(tid + 256, p[tid + 256]);
        } else {                                   // first/last tiles only
            auto ld = [&](int i4) {
                float v[4];
                #pragma unroll
                for (int j = 0; j < 4; ++j) {
                    const long g = g0 + 4L * i4 + j;
                    v[j] = (g >= 0 && g < NIN) ? xr[g] : 0.0f;
                }
                stc(i4, make_float4(v[0], v[1], v[2], v[3]));
            };
            ld(tid);
            if (tid < NV4 - 256) ld(tid + 256);
        }
        __syncthreads();                           // tile staged

        // A fragments: row r = lane&15 (k-local), K-pos = 32m + 8q + j.
        const int r = lane & 15, q = lane >> 4;
        const short* __restrict__ ap = &ldsb[24 * (16 * wv + r) + 8 * q];
        const short8v A0 = *reinterpret_cast<const short8v*>(ap);
        const short8v A1 = *reinterpret_cast<const short8v*>(ap + 32);
        const short8v A2 = *reinterpret_cast<const short8v*>(ap + 64);
        const short8v A3 = *reinterpret_cast<const short8v*>(ap + 96);

        float4v acc = {0.f, 0.f, 0.f, 0.f};
        acc = __builtin_amdgcn_mfma_f32_16x16x32_bf16(A0, B0, acc, 0, 0, 0);
        acc = __builtin_amdgcn_mfma_f32_16x16x32_bf16(A1, B1, acc, 0, 0, 0);
        acc = __builtin_amdgcn_mfma_f32_16x16x32_bf16(A2, B2, acc, 0, 0, 0);
        acc = __builtin_amdgcn_mfma_f32_16x16x32_bf16(A3, B3, acc, 0, 0, 0);

        // C/D: col=lane&15 (=phase d), row=(lane>>4)*4+reg (=k-local).
        const int d = lane & 15;
        if (d < 5) {
            const int kbase = 64 * ct + 16 * wv + 4 * q;
            float* __restrict__ yr = y + (size_t)row * NOUTR;
            #pragma unroll
            for (int j = 0; j < 4; ++j) {
                const int k = kbase + j;
                if (k < KTOT) yr[5 * (size_t)k + d] = acc[j];
            }
        }
    }
}

extern "C" void kernel_launch(void* const* d_in, const int* in_sizes, int n_in,
                              void* d_out, int out_size, void* d_ws, size_t ws_size,
                              hipStream_t stream) {
    const float* x = (const float*)d_in[0];
    const float* h = (const float*)d_in[1];        // 481 taps
    float* y = (float*)d_out;                      // 32 x 300000 f32
    unsigned short* Bpk = (unsigned short*)d_ws;   // 4KB packed B fragments

    prep_taps_kernel<<<8, 256, 0, stream>>>(h, Bpk);
    dim3 grid(NBX, NROWS);                         // 118 x 32, 256-thr blocks
    resample_kernel<<<grid, 256, 0, stream>>>(x, Bpk, y);
}